// Round 1
// baseline (65.011 us; speedup 1.0000x reference)
//
#include <hip/hip_runtime.h>
#include <math.h>

#define BATCH   512
#define NPATCH  196   // 14*14
#define NSAMP   (BATCH * NPATCH)

// ---------------------------------------------------------------------------
// Kernel 1: per patch-location mean and pi/2 * 1/(sd+1e-8) over B*4 elements
// ---------------------------------------------------------------------------
__global__ __launch_bounds__(256) void stats_kernel(const float* __restrict__ x,
                                                    float2* __restrict__ stats) {
    const int p = blockIdx.x;           // 0..195
    const int r = p / 14, c = p - r * 14;
    const int t = threadIdx.x;          // 256 threads

    float sum = 0.f, sq = 0.f;
    for (int b = t; b < BATCH; b += 256) {
        const float* base = x + b * 784 + (2 * r) * 28 + 2 * c;
        float2 v01 = *(const float2*)base;
        float2 v23 = *(const float2*)(base + 28);
        sum += v01.x + v01.y + v23.x + v23.y;
        sq  += v01.x * v01.x + v01.y * v01.y + v23.x * v23.x + v23.y * v23.y;
    }

    // wave64 shuffle reduce
    #pragma unroll
    for (int off = 32; off; off >>= 1) {
        sum += __shfl_down(sum, off, 64);
        sq  += __shfl_down(sq,  off, 64);
    }
    __shared__ float ssum[4], ssq[4];
    const int wave = t >> 6, lane = t & 63;
    if (lane == 0) { ssum[wave] = sum; ssq[wave] = sq; }
    __syncthreads();
    if (t == 0) {
        float S = ssum[0] + ssum[1] + ssum[2] + ssum[3];
        float Q = ssq[0]  + ssq[1]  + ssq[2]  + ssq[3];
        const float n = (float)(BATCH * 4);
        float m   = S / n;
        float var = (Q - S * S / n) / (n - 1.0f);
        float sd  = sqrtf(fmaxf(var, 0.f));
        // angle = (v - m)/(sd+1e-8) * pi; gates use theta/2 -> fold the 0.5 in
        float invh = 0.5f * 3.14159265358979323846f / (sd + 1e-8f);
        stats[p] = make_float2(m, invh);
    }
}

// ---------------------------------------------------------------------------
// Gate primitives: state idx = w0*8 + w1*4 + w2*2 + w3 (wire 0 = MSB)
// MASK = 8 >> wire. All fully unrolled -> arrays live in VGPRs.
// ---------------------------------------------------------------------------
template <int MASK>
__device__ __forceinline__ void ry_gate(float* sr, float* si, float c, float s) {
    #pragma unroll
    for (int i = 0; i < 16; ++i) {
        if ((i & MASK) == 0) {
            const int j = i | MASK;
            float a0 = sr[i], a1 = sr[j];
            sr[i] = c * a0 - s * a1;
            sr[j] = s * a0 + c * a1;
            float b0 = si[i], b1 = si[j];
            si[i] = c * b0 - s * b1;
            si[j] = s * b0 + c * b1;
        }
    }
}

template <int CMASK, int TMASK>
__device__ __forceinline__ void cnot_gate(float* sr, float* si) {
    #pragma unroll
    for (int i = 0; i < 16; ++i) {
        if ((i & CMASK) && !(i & TMASK)) {
            const int j = i | TMASK;
            float t;
            t = sr[i]; sr[i] = sr[j]; sr[j] = t;
            t = si[i]; si[i] = si[j]; si[j] = t;
        }
    }
}

template <int MASK>
__device__ __forceinline__ void rz_gate(float* sr, float* si, float pc, float ps) {
    // bit==0: amp *= (pc - i*ps);  bit==1: amp *= (pc + i*ps)
    #pragma unroll
    for (int i = 0; i < 16; ++i) {
        float r = sr[i], im = si[i];
        if (i & MASK) { sr[i] = r * pc - im * ps; si[i] = im * pc + r * ps; }
        else          { sr[i] = r * pc + im * ps; si[i] = im * pc - r * ps; }
    }
}

// ---------------------------------------------------------------------------
// Kernel 2: one thread per sample -> full 4-qubit circuit in registers
// ---------------------------------------------------------------------------
__global__ __launch_bounds__(256) void circuit_kernel(const float* __restrict__ x,
                                                      const float* __restrict__ params,
                                                      const float2* __restrict__ stats,
                                                      float* __restrict__ out) {
    const int tid = blockIdx.x * 256 + threadIdx.x;
    if (tid >= NSAMP) return;
    const int b = tid / NPATCH;
    const int p = tid - b * NPATCH;
    const int r = p / 14, c = p - r * 14;

    const float* base = x + b * 784 + (2 * r) * 28 + 2 * c;
    float2 v01 = *(const float2*)base;
    float2 v23 = *(const float2*)(base + 28);
    float2 st  = stats[p];

    // half-angles of the input RYs
    float h0 = (v01.x - st.x) * st.y;
    float h1 = (v01.y - st.x) * st.y;
    float h2 = (v23.x - st.x) * st.y;
    float h3 = (v23.y - st.x) * st.y;
    float c0, s0, c1, s1, c2, s2, c3, s3;
    __sincosf(h0, &s0, &c0);
    __sincosf(h1, &s1, &c1);
    __sincosf(h2, &s2, &c2);
    __sincosf(h3, &s3, &c3);

    // initial product state (real), |0000> rotated by RY(angle_i) on each wire
    float sr[16], si[16];
    #pragma unroll
    for (int i = 0; i < 16; ++i) {
        sr[i] = ((i & 8) ? s0 : c0) * ((i & 4) ? s1 : c1) *
                ((i & 2) ? s2 : c2) * ((i & 1) ? s3 : c3);
        si[i] = 0.0f;
    }

    // half-angles of the trainable params (2 layers x 4 wires x 3)
    float P[24];
    #pragma unroll
    for (int i = 0; i < 24; ++i) P[i] = 0.5f * params[i];

    #pragma unroll
    for (int l = 0; l < 2; ++l) {
        const int o = l * 12;
        float gs, gc;
        // RY(params[l][i][0])
        __sincosf(P[o + 0], &gs, &gc); ry_gate<8>(sr, si, gc, gs);
        __sincosf(P[o + 3], &gs, &gc); ry_gate<4>(sr, si, gc, gs);
        __sincosf(P[o + 6], &gs, &gc); ry_gate<2>(sr, si, gc, gs);
        __sincosf(P[o + 9], &gs, &gc); ry_gate<1>(sr, si, gc, gs);
        // CNOT(i, i+1)
        cnot_gate<8, 4>(sr, si);
        cnot_gate<4, 2>(sr, si);
        cnot_gate<2, 1>(sr, si);
        // RY(params[l][i][1])
        __sincosf(P[o + 1],  &gs, &gc); ry_gate<8>(sr, si, gc, gs);
        __sincosf(P[o + 4],  &gs, &gc); ry_gate<4>(sr, si, gc, gs);
        __sincosf(P[o + 7],  &gs, &gc); ry_gate<2>(sr, si, gc, gs);
        __sincosf(P[o + 10], &gs, &gc); ry_gate<1>(sr, si, gc, gs);
        // CNOT(i+1, i)
        cnot_gate<4, 8>(sr, si);
        cnot_gate<2, 4>(sr, si);
        cnot_gate<1, 2>(sr, si);
        // RZ(params[l][i][2])
        __sincosf(P[o + 2],  &gs, &gc); rz_gate<8>(sr, si, gc, gs);
        __sincosf(P[o + 5],  &gs, &gc); rz_gate<4>(sr, si, gc, gs);
        __sincosf(P[o + 8],  &gs, &gc); rz_gate<2>(sr, si, gc, gs);
        __sincosf(P[o + 11], &gs, &gc); rz_gate<1>(sr, si, gc, gs);
    }

    // probabilities and per-wire <Z>
    float pr[16];
    #pragma unroll
    for (int i = 0; i < 16; ++i) pr[i] = sr[i] * sr[i] + si[i] * si[i];

    float z0 = 0.f, z1 = 0.f, z2 = 0.f, z3 = 0.f;
    #pragma unroll
    for (int i = 0; i < 16; ++i) {
        z0 += (i & 8) ? -pr[i] : pr[i];
        z1 += (i & 4) ? -pr[i] : pr[i];
        z2 += (i & 2) ? -pr[i] : pr[i];
        z3 += (i & 1) ? -pr[i] : pr[i];
    }

    // out[b, p*4 + i] ; 16B aligned -> float4 store
    float4 zv = make_float4(z0, z1, z2, z3);
    *(float4*)(out + b * (NPATCH * 4) + p * 4) = zv;
}

extern "C" void kernel_launch(void* const* d_in, const int* in_sizes, int n_in,
                              void* d_out, int out_size, void* d_ws, size_t ws_size,
                              hipStream_t stream) {
    const float* x      = (const float*)d_in[0];   // (512, 28, 28) fp32
    const float* params = (const float*)d_in[1];   // (2, 4, 3) fp32
    float*       out    = (float*)d_out;           // (512, 784) fp32
    float2*      stats  = (float2*)d_ws;           // 196 x (mean, 0.5*pi/(sd+1e-8))

    stats_kernel<<<NPATCH, 256, 0, stream>>>(x, stats);

    const int nblk = (NSAMP + 255) / 256;          // 392
    circuit_kernel<<<nblk, 256, 0, stream>>>(x, params, stats, out);
}

// Round 2
// 63.043 us; speedup vs baseline: 1.0312x; 1.0312x over previous
//
#include <hip/hip_runtime.h>
#include <math.h>

#define BATCH   512
#define NPATCH  196   // 14*14

// ---------------------------------------------------------------------------
// Gate primitives: state idx = w0*8 + w1*4 + w2*2 + w3 (wire 0 = MSB)
// MASK = 8 >> wire. All fully unrolled -> arrays live in VGPRs.
// ---------------------------------------------------------------------------
template <int MASK>
__device__ __forceinline__ void ry_gate(float* sr, float* si, float c, float s) {
    #pragma unroll
    for (int i = 0; i < 16; ++i) {
        if ((i & MASK) == 0) {
            const int j = i | MASK;
            float a0 = sr[i], a1 = sr[j];
            sr[i] = c * a0 - s * a1;
            sr[j] = s * a0 + c * a1;
            float b0 = si[i], b1 = si[j];
            si[i] = c * b0 - s * b1;
            si[j] = s * b0 + c * b1;
        }
    }
}

template <int CMASK, int TMASK>
__device__ __forceinline__ void cnot_gate(float* sr, float* si) {
    #pragma unroll
    for (int i = 0; i < 16; ++i) {
        if ((i & CMASK) && !(i & TMASK)) {
            const int j = i | TMASK;
            float t;
            t = sr[i]; sr[i] = sr[j]; sr[j] = t;
            t = si[i]; si[i] = si[j]; si[j] = t;
        }
    }
}

template <int MASK>
__device__ __forceinline__ void rz_gate(float* sr, float* si, float pc, float ps) {
    // bit==0: amp *= (pc - i*ps);  bit==1: amp *= (pc + i*ps)
    #pragma unroll
    for (int i = 0; i < 16; ++i) {
        float r = sr[i], im = si[i];
        if (i & MASK) { sr[i] = r * pc - im * ps; si[i] = im * pc + r * ps; }
        else          { sr[i] = r * pc + im * ps; si[i] = im * pc - r * ps; }
    }
}

// Run the full circuit for one sample given the four input half-angles and
// the 24 precomputed (cos, sin) of the trainable half-angles (in registers).
__device__ __forceinline__ float4 run_circuit(float h0, float h1, float h2, float h3,
                                              const float* GC, const float* GS) {
    float c0, s0, c1, s1, c2, s2, c3, s3;
    __sincosf(h0, &s0, &c0);
    __sincosf(h1, &s1, &c1);
    __sincosf(h2, &s2, &c2);
    __sincosf(h3, &s3, &c3);

    // initial product state (real): |0000> rotated by RY(angle_i) on each wire
    float sr[16], si[16];
    #pragma unroll
    for (int i = 0; i < 16; ++i) {
        sr[i] = ((i & 8) ? s0 : c0) * ((i & 4) ? s1 : c1) *
                ((i & 2) ? s2 : c2) * ((i & 1) ? s3 : c3);
        si[i] = 0.0f;
    }

    #pragma unroll
    for (int l = 0; l < 2; ++l) {
        const int o = l * 12;
        // RY(params[l][i][0])
        ry_gate<8>(sr, si, GC[o + 0], GS[o + 0]);
        ry_gate<4>(sr, si, GC[o + 3], GS[o + 3]);
        ry_gate<2>(sr, si, GC[o + 6], GS[o + 6]);
        ry_gate<1>(sr, si, GC[o + 9], GS[o + 9]);
        // CNOT(i, i+1)
        cnot_gate<8, 4>(sr, si);
        cnot_gate<4, 2>(sr, si);
        cnot_gate<2, 1>(sr, si);
        // RY(params[l][i][1])
        ry_gate<8>(sr, si, GC[o + 1],  GS[o + 1]);
        ry_gate<4>(sr, si, GC[o + 4],  GS[o + 4]);
        ry_gate<2>(sr, si, GC[o + 7],  GS[o + 7]);
        ry_gate<1>(sr, si, GC[o + 10], GS[o + 10]);
        // CNOT(i+1, i)
        cnot_gate<4, 8>(sr, si);
        cnot_gate<2, 4>(sr, si);
        cnot_gate<1, 2>(sr, si);
        // RZ(params[l][i][2])
        rz_gate<8>(sr, si, GC[o + 2],  GS[o + 2]);
        rz_gate<4>(sr, si, GC[o + 5],  GS[o + 5]);
        rz_gate<2>(sr, si, GC[o + 8],  GS[o + 8]);
        rz_gate<1>(sr, si, GC[o + 11], GS[o + 11]);
    }

    // probabilities and per-wire <Z>
    float z0 = 0.f, z1 = 0.f, z2 = 0.f, z3 = 0.f;
    #pragma unroll
    for (int i = 0; i < 16; ++i) {
        float pr = sr[i] * sr[i] + si[i] * si[i];
        z0 += (i & 8) ? -pr : pr;
        z1 += (i & 4) ? -pr : pr;
        z2 += (i & 2) ? -pr : pr;
        z3 += (i & 1) ? -pr : pr;
    }
    return make_float4(z0, z1, z2, z3);
}

// ---------------------------------------------------------------------------
// Fused kernel: one block per patch location. Block computes the per-location
// normalization (mean, ddof-1 std over 512*4 values) in-block, then each
// thread evaluates the circuit for 2 batches.
// ---------------------------------------------------------------------------
__global__ __launch_bounds__(256) void fused_kernel(const float* __restrict__ x,
                                                    const float* __restrict__ params,
                                                    float* __restrict__ out) {
    __shared__ float s_gc[24], s_gs[24];
    __shared__ float s_sum[4], s_sq[4];
    __shared__ float s_m, s_invh;

    const int p = blockIdx.x;             // 0..195
    const int r = p / 14, c = p - r * 14;
    const int t = threadIdx.x;            // 0..255

    // 24 thread-uniform param sincos, once per block
    if (t < 24) {
        float gs, gc;
        __sincosf(0.5f * params[t], &gs, &gc);
        s_gc[t] = gc;
        s_gs[t] = gs;
    }

    // each thread owns batches t and t+256
    const float* base0 = x + t * 784 + (2 * r) * 28 + 2 * c;
    float2 a01 = *(const float2*)base0;
    float2 a23 = *(const float2*)(base0 + 28);
    const float* base1 = base0 + 256 * 784;
    float2 b01 = *(const float2*)base1;
    float2 b23 = *(const float2*)(base1 + 28);

    float sum = a01.x + a01.y + a23.x + a23.y + b01.x + b01.y + b23.x + b23.y;
    float sq  = a01.x * a01.x + a01.y * a01.y + a23.x * a23.x + a23.y * a23.y
              + b01.x * b01.x + b01.y * b01.y + b23.x * b23.x + b23.y * b23.y;

    // wave64 shuffle reduce, then 4-wave LDS combine
    #pragma unroll
    for (int off = 32; off; off >>= 1) {
        sum += __shfl_down(sum, off, 64);
        sq  += __shfl_down(sq,  off, 64);
    }
    const int wave = t >> 6, lane = t & 63;
    if (lane == 0) { s_sum[wave] = sum; s_sq[wave] = sq; }
    __syncthreads();
    if (t == 0) {
        float S = s_sum[0] + s_sum[1] + s_sum[2] + s_sum[3];
        float Q = s_sq[0]  + s_sq[1]  + s_sq[2]  + s_sq[3];
        const float n = (float)(BATCH * 4);
        float m   = S / n;
        float var = (Q - S * S / n) / (n - 1.0f);
        float sd  = sqrtf(fmaxf(var, 0.f));
        // angle = (v - m)/(sd+1e-8) * pi; gates use theta/2 -> fold the 0.5 in
        s_m    = m;
        s_invh = 0.5f * 3.14159265358979323846f / (sd + 1e-8f);
    }
    __syncthreads();

    const float m    = s_m;
    const float invh = s_invh;

    // pull gate sincos into registers (reused for both samples)
    float GC[24], GS[24];
    #pragma unroll
    for (int i = 0; i < 24; ++i) { GC[i] = s_gc[i]; GS[i] = s_gs[i]; }

    // sample 1: batch t
    float4 z = run_circuit((a01.x - m) * invh, (a01.y - m) * invh,
                           (a23.x - m) * invh, (a23.y - m) * invh, GC, GS);
    *(float4*)(out + t * (NPATCH * 4) + p * 4) = z;

    // sample 2: batch t + 256
    z = run_circuit((b01.x - m) * invh, (b01.y - m) * invh,
                    (b23.x - m) * invh, (b23.y - m) * invh, GC, GS);
    *(float4*)(out + (t + 256) * (NPATCH * 4) + p * 4) = z;
}

extern "C" void kernel_launch(void* const* d_in, const int* in_sizes, int n_in,
                              void* d_out, int out_size, void* d_ws, size_t ws_size,
                              hipStream_t stream) {
    const float* x      = (const float*)d_in[0];   // (512, 28, 28) fp32
    const float* params = (const float*)d_in[1];   // (2, 4, 3) fp32
    float*       out    = (float*)d_out;           // (512, 784) fp32

    fused_kernel<<<NPATCH, 256, 0, stream>>>(x, params, out);
}